// Round 8
// baseline (442.369 us; speedup 1.0000x reference)
//
#include <hip/hip_runtime.h>

// GraphSAGE 2-layer, fp32. N=100000, F_IN=64, H=128, E=1.6M.
// Round 7b: same as round 7 (gather de-VALU-ification: direct ssrc loads,
// 32-bit lshl_add addressing, u32 mask/shift bf16->f32, 8-deep unroll,
// nontemporal mean stores) with the compile fix: nontemporal_store needs a
// clang ext_vector type (f32x4), not HIP_vector_type float4.
// CSR build, dense split-bf16 MFMA unchanged from round 6.

#define EPB 16384          // edges per scatter block
#define MAXNB 1024         // max dst buckets (N<=131072)

typedef __attribute__((ext_vector_type(8))) short bf16x8;  // MFMA A/B frag
typedef __attribute__((ext_vector_type(4))) float f32x4;   // MFMA C/D frag

union ABu { unsigned u[4]; bf16x8 v; };

__device__ inline unsigned short f2bf_rne(float f) {
    unsigned u = __float_as_uint(f);
    return (unsigned short)((u + 0x7FFFu + ((u >> 16) & 1u)) >> 16);
}

// split 8 fp32 -> hi (bf16 trunc) + lo (bf16 of exact residual)
__device__ inline void splitA(const f32x4 fA, const f32x4 fB,
                              bf16x8& hi, bf16x8& lo) {
    ABu H, L;
    float f[8] = {fA.x, fA.y, fA.z, fA.w, fB.x, fB.y, fB.z, fB.w};
    #pragma unroll
    for (int p = 0; p < 4; ++p) {
        unsigned u0 = __float_as_uint(f[2*p]);
        unsigned u1 = __float_as_uint(f[2*p+1]);
        unsigned h0 = u0 & 0xFFFF0000u;
        unsigned h1 = u1 & 0xFFFF0000u;
        H.u[p] = (u0 >> 16) | h1;
        float r0 = f[2*p]   - __uint_as_float(h0);
        float r1 = f[2*p+1] - __uint_as_float(h1);
        L.u[p] = (__float_as_uint(r0) >> 16) | (__float_as_uint(r1) & 0xFFFF0000u);
    }
    hi = H.v; lo = L.v;
}

// ---------------- fp32 -> bf16 (RNE) bulk convert ----------------
__global__ __launch_bounds__(256) void cvt_bf16_kernel(
    const float* __restrict__ in, unsigned short* __restrict__ out, int n)
{
    int i = (blockIdx.x * 256 + threadIdx.x) * 4;
    if (i >= n) return;
    float4 v = *reinterpret_cast<const float4*>(&in[i]);
    ushort4 o;
    o.x = f2bf_rne(v.x); o.y = f2bf_rne(v.y);
    o.z = f2bf_rne(v.z); o.w = f2bf_rne(v.w);
    *reinterpret_cast<ushort4*>(&out[i]) = o;
}

// ---------------- step 1: per-block bucket histogram ----------------
__global__ __launch_bounds__(256) void count_blocks_kernel(
    const int* __restrict__ ei, int* __restrict__ blockCounts, // [NBLK][NB]
    int E, int NB)
{
    __shared__ int hist[MAXNB];
    for (int i = threadIdx.x; i < NB; i += 256) hist[i] = 0;
    __syncthreads();
    int e0 = blockIdx.x * EPB;
    int e1 = min(e0 + EPB, E);
    for (int e = e0 + threadIdx.x; e < e1; e += 256)
        atomicAdd(&hist[ei[E + e] >> 7], 1);
    __syncthreads();
    for (int i = threadIdx.x; i < NB; i += 256)
        blockCounts[blockIdx.x * NB + i] = hist[i];
}

// ---------------- step 2: deterministic 2-level scan ----------------
__global__ __launch_bounds__(1024) void scan_buckets_kernel(
    const int* __restrict__ blockCounts,   // [NBLK][NB]
    int* __restrict__ blockBase,           // [NBLK][NB]
    int* __restrict__ bucketBase,          // [NB+1]
    int NB, int NBLK)
{
    __shared__ int tot[1024];
    int t = threadIdx.x;
    int run = 0;
    if (t < NB) {
        for (int k = 0; k < NBLK; ++k) {
            int c = blockCounts[k * NB + t];
            blockBase[k * NB + t] = run;   // prefix within bucket
            run += c;
        }
    }
    tot[t] = run;
    __syncthreads();
    for (int o = 1; o < 1024; o <<= 1) {
        int a = (t >= o) ? tot[t - o] : 0;
        __syncthreads();
        tot[t] += a;
        __syncthreads();
    }
    if (t < NB) {
        int base = tot[t] - run;           // exclusive prefix
        bucketBase[t] = base;
        for (int k = 0; k < NBLK; ++k) blockBase[k * NB + t] += base;
    }
    if (t == 0) bucketBase[NB] = tot[1023];   // == E
}

// ---------------- step 3: write pairs into block-owned runs ----------------
__global__ __launch_bounds__(256) void write_pairs_kernel(
    const int* __restrict__ ei, const int* __restrict__ blockBase,
    unsigned* __restrict__ pairs, int E, int NB)
{
    __shared__ int cur[MAXNB];
    for (int i = threadIdx.x; i < NB; i += 256)
        cur[i] = blockBase[blockIdx.x * NB + i];
    __syncthreads();
    int e0 = blockIdx.x * EPB;
    int e1 = min(e0 + EPB, E);
    for (int e = e0 + threadIdx.x; e < e1; e += 256) {
        int s = ei[e];
        int d = ei[E + e];
        int p = atomicAdd(&cur[d >> 7], 1);      // LDS atomic, ~21-deep
        pairs[p] = ((unsigned)(d & 127) << 25) | (unsigned)s;
    }
}

// ---------------- step 4: per-bucket finalize: rowptr + sorted ssrc --------
__global__ __launch_bounds__(256) void bucket_finalize_kernel(
    const unsigned* __restrict__ pairs, const int* __restrict__ bucketBase,
    int* __restrict__ rowptr, int* __restrict__ ssrc, int N)
{
    __shared__ int hist[128];
    __shared__ int scn[128];
    __shared__ int cur[128];
    int t = threadIdx.x;
    int b = blockIdx.x;
    int segS = bucketBase[b], segE = bucketBase[b + 1];
    if (t < 128) hist[t] = 0;
    __syncthreads();
    for (int i = segS + t; i < segE; i += 256)
        atomicAdd(&hist[pairs[i] >> 25], 1);
    __syncthreads();
    if (t < 128) scn[t] = hist[t];
    __syncthreads();
    for (int o = 1; o < 128; o <<= 1) {
        int a = 0;
        if (t < 128 && t >= o) a = scn[t - o];
        __syncthreads();
        if (t < 128) scn[t] += a;
        __syncthreads();
    }
    if (t < 128) {
        int start = segS + scn[t] - hist[t];     // exclusive prefix
        cur[t] = start;
        int node = b * 128 + t;
        if (node < N) rowptr[node] = start;
    }
    if (b == 0 && t == 0) rowptr[N] = bucketBase[gridDim.x];
    __syncthreads();
    for (int i = segS + t; i < segE; i += 256) {
        unsigned p = pairs[i];
        int pos = atomicAdd(&cur[p >> 25], 1);
        ssrc[pos] = (int)(p & 0x1FFFFFFu);
    }
}

// ---------------- weight prep: split + fragment-order ----------------
__global__ __launch_bounds__(256) void prep_w_kernel(
    const float* __restrict__ Wl, const float* __restrict__ Wr, int F,
    short* __restrict__ w0f, short* __restrict__ w1f, int nfrag)
{
    int t = blockIdx.x * 256 + threadIdx.x;   // one thread per (frag, lane)
    if (t >= nfrag * 64) return;
    int lane = t & 63, fr = t >> 6;
    int j  = fr & 7, ks = fr >> 3;
    int col = j * 16 + (lane & 15);
    int k0  = ks * 32 + (lane >> 4) * 8;
    #pragma unroll
    for (int e = 0; e < 8; ++e) {
        int k = k0 + e;
        float w = (k < F) ? Wl[col * F + k] : Wr[col * F + (k - F)];
        unsigned u = __float_as_uint(w);
        unsigned h = u & 0xFFFF0000u;
        float r = w - __uint_as_float(h);
        w0f[t * 8 + e] = (short)(u >> 16);
        w1f[t * 8 + e] = (short)(__float_as_uint(r) >> 16);
    }
}

// ---------------- gather aggregation from bf16 rows ----------------
// Lane covers an 8B chunk (4 feats); C = F/4 lanes per row, G = 64/C edges
// in flight per step. Direct ssrc loads (HW broadcast within a C-group),
// 32-bit lshl_add addressing, mask/shift bf16 conversion, 8-deep unroll.
template<int F>
__global__ __launch_bounds__(256) void agg_gather_kernel(
    const int* __restrict__ rowptr, const int* __restrict__ ssrc,
    const unsigned short* __restrict__ feat,   // [N][F] bf16
    float* __restrict__ mean, int N)           // [N][F] fp32
{
    constexpr int C  = F / 4;        // lanes per row
    constexpr int G  = 64 / C;       // edges per step
    constexpr int SH = (F == 128) ? 8 : 7;   // log2(row bytes)
    int wave = threadIdx.x >> 6;
    int lane = threadIdx.x & 63;
    int n = blockIdx.x * 4 + wave;
    if (n >= N) return;
    int rp = rowptr[n], re = rowptr[n + 1];
    const int chunk = lane & (C - 1);
    const int grp   = lane / C;
    const unsigned cb = (unsigned)chunk * 8;
    const char* fbase = (const char*)feat;

    float a0 = 0.f, a1 = 0.f, a2 = 0.f, a3 = 0.f;

    int e = rp + grp;
    // 8-step unrolled main loop (all 8 edges valid for this grp)
    while (e + 7 * G < re) {
        int s[8];
        #pragma unroll
        for (int i = 0; i < 8; ++i) s[i] = ssrc[e + i * G];
        #pragma unroll
        for (int i = 0; i < 8; ++i) {
            unsigned off = ((unsigned)s[i] << SH) + cb;
            uint2 p = *reinterpret_cast<const uint2*>(fbase + off);
            a0 += __uint_as_float(p.x << 16);
            a1 += __uint_as_float(p.x & 0xFFFF0000u);
            a2 += __uint_as_float(p.y << 16);
            a3 += __uint_as_float(p.y & 0xFFFF0000u);
        }
        e += 8 * G;
    }
    while (e < re) {
        unsigned off = ((unsigned)ssrc[e] << SH) + cb;
        uint2 p = *reinterpret_cast<const uint2*>(fbase + off);
        a0 += __uint_as_float(p.x << 16);
        a1 += __uint_as_float(p.x & 0xFFFF0000u);
        a2 += __uint_as_float(p.y << 16);
        a3 += __uint_as_float(p.y & 0xFFFF0000u);
        e += G;
    }

    // reduce across the G lane-groups
    #pragma unroll
    for (int o = C; o < 64; o <<= 1) {
        a0 += __shfl_xor(a0, o);
        a1 += __shfl_xor(a1, o);
        a2 += __shfl_xor(a2, o);
        a3 += __shfl_xor(a3, o);
    }
    if (lane < C) {
        float inv = 1.0f / (float)max(re - rp, 1);
        f32x4 o4 = {a0 * inv, a1 * inv, a2 * inv, a3 * inv};
        __builtin_nontemporal_store(o4,
            reinterpret_cast<f32x4*>(&mean[(size_t)n * F + lane * 4]));
    }
}

// ---------------- dense layer via split-bf16 MFMA ----------------
template<int F, bool RELU, bool EMIT_BF16>
__global__ __launch_bounds__(256, 2) void dense_mfma_kernel(
    const float* __restrict__ left,    // mean [N][F]
    const float* __restrict__ right,   // x or h [N][F]
    const short* __restrict__ w0f,     // [(2F/32)*8][64][8]
    const short* __restrict__ w1f,
    const float* __restrict__ bl,      // [128]
    float* __restrict__ out,           // [N][128]
    unsigned short* __restrict__ outb, // [N][128] bf16 (EMIT_BF16 only)
    int N)
{
    constexpr int NS = (2 * F) / 32;   // k-steps
    const int tid  = threadIdx.x;
    const int lane = tid & 63;
    const int wv   = tid >> 6;
    const int r16  = lane & 15;
    const int kg   = lane >> 4;
    const int rowBase = blockIdx.x * 128 + wv * 32;

    const int row0 = min(rowBase + r16,      N - 1);
    const int row1 = min(rowBase + 16 + r16, N - 1);

    f32x4 acc[2][8];
    #pragma unroll
    for (int rt = 0; rt < 2; ++rt)
        #pragma unroll
        for (int j = 0; j < 8; ++j)
            acc[rt][j] = (f32x4){0.f, 0.f, 0.f, 0.f};

    #pragma unroll
    for (int ks = 0; ks < NS; ++ks) {
        const bool Lh = (ks * 32) < F;
        const float* __restrict__ src = Lh ? left : right;
        const int koff = ks * 32 - (Lh ? 0 : F) + kg * 8;

        bf16x8 a0[2], a1[2];
        {
            const float* ap0 = src + (size_t)row0 * F + koff;
            splitA(*reinterpret_cast<const f32x4*>(ap0),
                   *reinterpret_cast<const f32x4*>(ap0 + 4), a0[0], a1[0]);
            const float* ap1 = src + (size_t)row1 * F + koff;
            splitA(*reinterpret_cast<const f32x4*>(ap1),
                   *reinterpret_cast<const f32x4*>(ap1 + 4), a0[1], a1[1]);
        }

        #pragma unroll
        for (int j = 0; j < 8; ++j) {
            const size_t fb = (((size_t)(ks * 8 + j)) * 64 + lane) * 8;
            const bf16x8 b0 = *reinterpret_cast<const bf16x8*>(&w0f[fb]);
            const bf16x8 b1 = *reinterpret_cast<const bf16x8*>(&w1f[fb]);
            #pragma unroll
            for (int rt = 0; rt < 2; ++rt) {
                acc[rt][j] = __builtin_amdgcn_mfma_f32_16x16x32_bf16(
                    a0[rt], b0, acc[rt][j], 0, 0, 0);
                acc[rt][j] = __builtin_amdgcn_mfma_f32_16x16x32_bf16(
                    a0[rt], b1, acc[rt][j], 0, 0, 0);
                acc[rt][j] = __builtin_amdgcn_mfma_f32_16x16x32_bf16(
                    a1[rt], b0, acc[rt][j], 0, 0, 0);
            }
        }
    }

    #pragma unroll
    for (int j = 0; j < 8; ++j) {
        const int col = j * 16 + r16;
        const float b = bl[col];
        #pragma unroll
        for (int rt = 0; rt < 2; ++rt) {
            const int rb = rowBase + rt * 16 + kg * 4;
            #pragma unroll
            for (int i = 0; i < 4; ++i) {
                int row = rb + i;
                if (row < N) {
                    float v = acc[rt][j][i] + b;
                    if (RELU) v = fmaxf(v, 0.f);
                    out[(size_t)row * 128 + col] = v;
                    if (EMIT_BF16) outb[(size_t)row * 128 + col] = f2bf_rne(v);
                }
            }
        }
    }
}

extern "C" void kernel_launch(void* const* d_in, const int* in_sizes, int n_in,
                              void* d_out, int out_size, void* d_ws, size_t ws_size,
                              hipStream_t stream) {
    const float* x   = (const float*)d_in[0];
    const int*   ei  = (const int*)d_in[1];
    const float* Wl1 = (const float*)d_in[2];
    const float* bl1 = (const float*)d_in[3];
    const float* Wr1 = (const float*)d_in[4];
    const float* Wl2 = (const float*)d_in[5];
    const float* bl2 = (const float*)d_in[6];
    const float* Wr2 = (const float*)d_in[7];
    float* out = (float*)d_out;

    const int N    = in_sizes[0] / 64;     // 100000
    const int E    = in_sizes[1] / 2;      // 1600000
    const int NB   = (N + 127) / 128;      // dst buckets (782)
    const int NBLK = (E + EPB - 1) / EPB;  // scatter blocks (98)

    // ws layout: ints | short weight frags | floats
    int* ssrc       = (int*)d_ws;
    int* rowptr     = ssrc + E;                  // [N+1]
    int* bucketBase = rowptr + (N + 1);          // [NB+1]
    int* blockCounts= bucketBase + (NB + 1);     // [NBLK*NB]
    int* blockBase  = blockCounts + NB * NBLK;   // [NBLK*NB]
    short* w0f1 = (short*)(blockBase + NB * NBLK);   // 32 frags * 512
    short* w1f1 = w0f1 + 32 * 512;
    short* w0f2 = w1f1 + 32 * 512;                   // 64 frags * 512
    short* w1f2 = w0f2 + 64 * 512;
    size_t shortEnd = (size_t)(w1f2 + 64 * 512 - (short*)d_ws);
    size_t floatOff = (shortEnd * 2 + 15) / 16 * 4;  // 16B-aligned float index
    float* meanbuf = (float*)d_ws + floatOff;        // [N][128]
    float* h       = meanbuf + (size_t)N * 128;      // [N][128]
    // aliases (disjoint in time):
    //   pairs = meanbuf[0 : E]            (dead before gather1 writes mean64)
    //   xb    = meanbuf[8M : 8M+6.4M]     (ushort; dead before gather2's mean128)
    //   hb    = d_out                      (dead before dense2 writes out)
    unsigned* pairs     = (unsigned*)meanbuf;
    unsigned short* xb  = (unsigned short*)(meanbuf + 8000000);
    unsigned short* hb  = (unsigned short*)d_out;

    // bf16 copy of x for gather1
    cvt_bf16_kernel<<<(N * 64 / 4 + 255) / 256, 256, 0, stream>>>(x, xb, N * 64);

    // atomic-free CSR build
    count_blocks_kernel<<<NBLK, 256, 0, stream>>>(ei, blockCounts, E, NB);
    scan_buckets_kernel<<<1, 1024, 0, stream>>>(blockCounts, blockBase, bucketBase, NB, NBLK);
    write_pairs_kernel<<<NBLK, 256, 0, stream>>>(ei, blockBase, pairs, E, NB);
    bucket_finalize_kernel<<<NB, 256, 0, stream>>>(pairs, bucketBase, rowptr, ssrc, N);

    // weight prep (fragment-ordered split-bf16)
    prep_w_kernel<<<(32 * 64 + 255) / 256, 256, 0, stream>>>(Wl1, Wr1, 64, w0f1, w1f1, 32);
    prep_w_kernel<<<(64 * 64 + 255) / 256, 256, 0, stream>>>(Wl2, Wr2, 128, w0f2, w1f2, 64);

    const int dgrid = (N + 127) / 128;

    // layer 1: gather bf16(x) -> mean64; dense emits h fp32 + hb bf16
    agg_gather_kernel<64><<<(N + 3) / 4, 256, 0, stream>>>(rowptr, ssrc, xb, meanbuf, N);
    dense_mfma_kernel<64, true, true><<<dgrid, 256, 0, stream>>>(
        meanbuf, x, w0f1, w1f1, bl1, h, hb, N);

    // layer 2: gather bf16(h) -> mean128; dense writes final out
    agg_gather_kernel<128><<<(N + 3) / 4, 256, 0, stream>>>(rowptr, ssrc, hb, meanbuf, N);
    dense_mfma_kernel<128, false, false><<<dgrid, 256, 0, stream>>>(
        meanbuf, h, w0f2, w1f2, bl2, out, nullptr, N);
}